// Round 1
// baseline (42213.193 us; speedup 1.0000x reference)
//
#include <hip/hip_runtime.h>

// LSTM  B=64, T=2048, I=H=512, fp32 in/out.
// Phase A: convert x to bf16; pack W_i (4 gates) transposed+bf16; bias.
// Phase B: Gx[t][j][bg][r][c] = x_t @ W_i + b  (bf16 MFMA GEMM, M=131072,N=2048,K=512)
// Phase C: persistent recurrent kernel: 4 independent batch-groups x 32 column-wgs,
//          W_h slice in VGPRs, h broadcast via global double buffer + flag sync.

typedef __attribute__((ext_vector_type(8))) short bf16x8;
typedef __attribute__((ext_vector_type(4))) float f32x4;

#define T_STEPS 2048

__device__ __forceinline__ unsigned short f2bf(float f) {
  union { float f; unsigned u; } v; v.f = f;
  unsigned r = v.u + 0x7fffu + ((v.u >> 16) & 1u);   // RNE
  return (unsigned short)(r >> 16);
}
__device__ __forceinline__ float bf2f(unsigned short b) {
  union { unsigned u; float f; } v; v.u = ((unsigned)b) << 16;
  return v.f;
}
__device__ __forceinline__ float sigm(float x)  { return 1.f / (1.f + __expf(-x)); }
__device__ __forceinline__ float tanhx(float x) { return 2.f / (1.f + __expf(-2.f * x)) - 1.f; }

// ---------------- Phase A: x fp32 -> bf16 ----------------
__global__ __launch_bounds__(256) void k_cvt(const float* __restrict__ x,
                                             unsigned short* __restrict__ xb, int n4) {
  int stride = gridDim.x * blockDim.x;
  for (int i = blockIdx.x * blockDim.x + threadIdx.x; i < n4; i += stride) {
    float4 v = ((const float4*)x)[i];
    ushort4 o;
    o.x = f2bf(v.x); o.y = f2bf(v.y); o.z = f2bf(v.z); o.w = f2bf(v.w);
    ((ushort4*)xb)[i] = o;
  }
}

// ---------------- Phase A: W_i -> Wt[p][k] bf16 (p = j*64 + g*16 + hl), bias ----------------
__global__ __launch_bounds__(128) void k_prep_w(
    const float* __restrict__ wi, const float* __restrict__ wf,
    const float* __restrict__ wg, const float* __restrict__ wo,
    const float* __restrict__ bii, const float* __restrict__ bif,
    const float* __restrict__ big, const float* __restrict__ bio,
    const float* __restrict__ bhi, const float* __restrict__ bhf,
    const float* __restrict__ bhg, const float* __restrict__ bho,
    unsigned short* __restrict__ Wt, float* __restrict__ biasp) {
  int p = blockIdx.x;
  int g = (p >> 4) & 3, jj = p >> 6, hl = p & 15;
  int hcol = jj * 16 + hl;
  const float* w = (g == 0) ? wi : (g == 1) ? wf : (g == 2) ? wg : wo;
  for (int k = threadIdx.x; k < 512; k += 128)
    Wt[(long)p * 512 + k] = f2bf(w[(long)k * 512 + hcol]);
  if (threadIdx.x == 0) {
    const float* bi = (g == 0) ? bii : (g == 1) ? bif : (g == 2) ? big : bio;
    const float* bh = (g == 0) ? bhi : (g == 1) ? bhf : (g == 2) ? bhg : bho;
    biasp[p] = bi[hcol] + bh[hcol];
  }
}

// ---------------- Phase B: Gx = x @ Wt^T + bias (bf16 MFMA, 128x128 tile, BK=64) ----------------
__global__ __launch_bounds__(256) void k_gemm_x(
    const unsigned short* __restrict__ A,   // [131072][512] bf16
    const unsigned short* __restrict__ Bt,  // [2048][512] bf16
    const float* __restrict__ biasp,        // [2048]
    unsigned short* __restrict__ Gx) {      // [T][32][4][16][64] bf16
  __shared__ unsigned short lds[16384];     // 32 KB: lA[128][64] | lB[128][64], reused for epilogue
  unsigned short* lA = lds;
  unsigned short* lB = lds + 8192;
  const int tid  = threadIdx.x;
  const int lane = tid & 63;
  const int wave = tid >> 6;
  const long m0  = (long)blockIdx.x * 128;
  const int p0   = blockIdx.y * 128;
  const int wm   = (wave >> 1) * 64;
  const int wn   = (wave & 1) * 64;
  const int lrow = lane & 15;
  const int quad = lane >> 4;

  f32x4 acc[4][4] = {};

  for (int kb = 0; kb < 512; kb += 64) {
    __syncthreads();
#pragma unroll
    for (int it = 0; it < 4; ++it) {          // stage 128 rows x 64 k, XOR-swizzled (16B units)
      int ci = it * 256 + tid;
      int row = ci >> 3, c8 = ci & 7;
      int c8p = c8 ^ (row & 7);
      *(int4*)&lA[row * 64 + c8p * 8] = *(const int4*)(A + (m0 + row) * 512 + kb + c8 * 8);
      *(int4*)&lB[row * 64 + c8p * 8] = *(const int4*)(Bt + (long)(p0 + row) * 512 + kb + c8 * 8);
    }
    __syncthreads();
#pragma unroll
    for (int kk = 0; kk < 2; ++kk) {
      int c8 = kk * 4 + quad;
      bf16x8 af[4], bfr[4];
#pragma unroll
      for (int i = 0; i < 4; ++i) {
        int m = wm + i * 16 + lrow;
        af[i]  = *(const bf16x8*)&lA[m * 64 + ((c8 ^ (m & 7)) * 8)];
        int p = wn + i * 16 + lrow;
        bfr[i] = *(const bf16x8*)&lB[p * 64 + ((c8 ^ (p & 7)) * 8)];
      }
#pragma unroll
      for (int i = 0; i < 4; ++i)
#pragma unroll
        for (int n = 0; n < 4; ++n)
          acc[i][n] = __builtin_amdgcn_mfma_f32_16x16x32_bf16(af[i], bfr[n], acc[i][n], 0, 0, 0);
    }
  }

  float bl[4];
#pragma unroll
  for (int n = 0; n < 4; ++n) bl[n] = biasp[p0 + wn + n * 16 + lrow];

  __syncthreads();
#pragma unroll
  for (int i = 0; i < 4; ++i)
#pragma unroll
    for (int n = 0; n < 4; ++n) {
      int col = wn + n * 16 + lrow;
#pragma unroll
      for (int r4 = 0; r4 < 4; ++r4) {
        int row = wm + i * 16 + quad * 4 + r4;          // C/D: col=lane&15, row=quad*4+reg
        lds[row * 128 + col] = f2bf(acc[i][n][r4] + bl[n]);
      }
    }
  __syncthreads();
  {
    int row = tid >> 1, half = tid & 1;
    long m = m0 + row;
    int b = (int)(m >> 11), t = (int)(m & 2047);
    int bg = b >> 4, r = b & 15;
    int jj = (p0 >> 6) + half;
    unsigned short* dst = Gx + ((((long)t * 32 + jj) * 4 + bg) * 16 + r) * 64;
    const unsigned short* src = lds + row * 128 + half * 64;
#pragma unroll
    for (int c = 0; c < 8; ++c)
      *(int4*)(dst + c * 8) = *(const int4*)(src + c * 8);
  }
}

// ---------------- Phase C: persistent recurrence ----------------
// 128 wgs = 4 batch-groups (16 rows) x 32 col-wgs (16 hcols x 4 gates).
// wave w computes gate w; W_h fragment slice lives in VGPRs for all 2048 steps.
__global__ __launch_bounds__(256, 1) void k_lstm(
    const float* __restrict__ Whi, const float* __restrict__ Whf,
    const float* __restrict__ Whg, const float* __restrict__ Who,
    const unsigned short* __restrict__ Gx,
    unsigned short* __restrict__ hbuf,   // [2][4][16][512] bf16, zeroed
    unsigned int* __restrict__ flags,    // [4][32], zeroed
    float* __restrict__ out) {
  const int wg   = blockIdx.x;
  const int bg   = wg >> 5;
  const int j    = wg & 31;
  const int tid  = threadIdx.x;
  const int lane = tid & 63;
  const int wave = tid >> 6;          // gate id
  const int hl   = lane & 15;
  const int quad = lane >> 4;

  __shared__ float gl[4][16][16];     // [gate][r][hl] raw h-part

  const float* Wh = (wave == 0) ? Whi : (wave == 1) ? Whf : (wave == 2) ? Whg : Who;
  const int hcol = j * 16 + hl;
  bf16x8 wfrag[16];                   // B-operand: B[k][n=lane&15], k = kk*32 + quad*8 + i
#pragma unroll
  for (int kk = 0; kk < 16; ++kk) {
    int kbase = kk * 32 + quad * 8;
    bf16x8 t;
#pragma unroll
    for (int i = 0; i < 8; ++i)
      t[i] = (short)f2bf(Wh[(long)(kbase + i) * 512 + hcol]);
    wfrag[kk] = t;
  }

  unsigned short* hb0 = hbuf;
  unsigned short* hb1 = hbuf + 4 * 16 * 512;
  unsigned int* myflags = flags + bg * 32;
  const int fl  = lane & 31;
  const int er  = tid >> 4;           // epilogue row (batch row within group)
  const int ehl = tid & 15;           // epilogue hcol low
  const int r_a = lane & 15;          // MFMA A row

  float c_val = 0.f;
  float h_val = 0.f;

  for (int s = 0; s < T_STEPS; ++s) {
    if (s > 0) {
      while (__hip_atomic_load(&myflags[fl], __ATOMIC_ACQUIRE,
                               __HIP_MEMORY_SCOPE_AGENT) < (unsigned)s) {}
    }
    const unsigned short* hcur = (s & 1) ? hb1 : hb0;
    unsigned short* hnxt       = (s & 1) ? hb0 : hb1;

    // x-gate contributions (issued early, consumed in epilogue)
    const unsigned short* gxp = Gx + ((((long)s * 32 + j) * 4 + bg) * 16 + er) * 64 + ehl;
    unsigned short gxi = gxp[0], gxf = gxp[16], gxg = gxp[32], gxo = gxp[48];

    // A fragments: h[r = lane&15][k], 16B per k-chunk
    const unsigned short* hsrc = hcur + (bg * 16 + r_a) * 512 + quad * 8;
    bf16x8 af[16];
#pragma unroll
    for (int kk = 0; kk < 16; ++kk)
      af[kk] = *(const bf16x8*)(hsrc + kk * 32);

    f32x4 acc = {0.f, 0.f, 0.f, 0.f};
#pragma unroll
    for (int kk = 0; kk < 16; ++kk)
      acc = __builtin_amdgcn_mfma_f32_16x16x32_bf16(af[kk], wfrag[kk], acc, 0, 0, 0);

#pragma unroll
    for (int i = 0; i < 4; ++i)
      gl[wave][quad * 4 + i][hl] = acc[i];
    __syncthreads();

    float ui = gl[0][er][ehl] + bf2f(gxi);
    float uf = gl[1][er][ehl] + bf2f(gxf);
    float ug = gl[2][er][ehl] + bf2f(gxg);
    float uo = gl[3][er][ehl] + bf2f(gxo);
    float ig = sigm(ui), fg = sigm(uf), gg = tanhx(ug), og = sigm(uo);
    c_val = fg * c_val + ig * gg;
    h_val = og * tanhx(c_val);

    hnxt[(bg * 16 + er) * 512 + j * 16 + ehl] = f2bf(h_val);
    __threadfence();                 // agent-scope: make h stores visible
    __syncthreads();                 // all threads' stores+fences done; also guards gl reuse
    if (tid == 0)
      __hip_atomic_store(&myflags[j], (unsigned)(s + 1), __ATOMIC_RELEASE,
                         __HIP_MEMORY_SCOPE_AGENT);
  }

  int b = bg * 16 + er;
  out[(long)b * 512 + j * 16 + ehl]         = h_val;   // h_T
  out[32768 + (long)b * 512 + j * 16 + ehl] = c_val;   // c_T
}

// ---------------- launcher ----------------
extern "C" void kernel_launch(void* const* d_in, const int* in_sizes, int n_in,
                              void* d_out, int out_size, void* d_ws, size_t ws_size,
                              hipStream_t stream) {
  const float* x    = (const float*)d_in[0];
  const float* w_ii = (const float*)d_in[1];
  const float* w_hi = (const float*)d_in[2];
  const float* b_ii = (const float*)d_in[3];
  const float* b_hi = (const float*)d_in[4];
  const float* w_if = (const float*)d_in[5];
  const float* w_hf = (const float*)d_in[6];
  const float* b_if_= (const float*)d_in[7];
  const float* b_hf = (const float*)d_in[8];
  const float* w_ig = (const float*)d_in[9];
  const float* w_hg = (const float*)d_in[10];
  const float* b_ig = (const float*)d_in[11];
  const float* b_hg = (const float*)d_in[12];
  const float* w_io = (const float*)d_in[13];
  const float* w_ho = (const float*)d_in[14];
  const float* b_io = (const float*)d_in[15];
  const float* b_ho = (const float*)d_in[16];

  char* ws = (char*)d_ws;
  // layout: Gx 512MB | xb 128MB | Wt 2MB | biasp 8KB | hbuf 128KB | flags 512B
  unsigned short* Gx   = (unsigned short*)(ws);
  unsigned short* xb   = (unsigned short*)(ws + 536870912L);
  unsigned short* Wt   = (unsigned short*)(ws + 671088640L);
  float* biasp         = (float*)(ws + 673185792L);
  unsigned short* hbuf = (unsigned short*)(ws + 673193984L);
  // flags directly after hbuf (contiguous for one memset)

  hipMemsetAsync(hbuf, 0, 131072 + 512, stream);
  unsigned int* flags = (unsigned int*)(ws + 673193984L + 131072L);

  k_cvt<<<8192, 256, 0, stream>>>(x, xb, (64 * 2048 * 512) / 4);
  k_prep_w<<<2048, 128, 0, stream>>>(w_ii, w_if, w_ig, w_io,
                                     b_ii, b_if_, b_ig, b_io,
                                     b_hi, b_hf, b_hg, b_ho,
                                     Wt, biasp);
  k_gemm_x<<<dim3(1024, 16), 256, 0, stream>>>(xb, Wt, biasp, Gx);
  k_lstm<<<128, 256, 0, stream>>>(w_hi, w_hf, w_hg, w_ho, Gx, hbuf, flags, (float*)d_out);
}

// Round 2
// 12809.019 us; speedup vs baseline: 3.2956x; 3.2956x over previous
//
#include <hip/hip_runtime.h>

// LSTM  B=64, T=2048, I=H=512, fp32 in/out.
// Phase A: convert x to bf16; pack W_i (4 gates) transposed+bf16; bias.
// Phase B: Gx[t][j][bg][r][c] = x_t @ W_i + b  (bf16 MFMA GEMM, M=131072,N=2048,K=512)
// Phase C: persistent recurrent kernel: 4 independent batch-groups x 32 column-wgs,
//          W_h slice pinned in VGPRs, h broadcast via LLC-coherent relaxed atomics
//          (no threadfence / no acquire buffer_inv on the hot path).

typedef __attribute__((ext_vector_type(8))) short bf16x8;
typedef __attribute__((ext_vector_type(4))) float f32x4;

#define T_STEPS 2048

__device__ __forceinline__ unsigned short f2bf(float f) {
  union { float f; unsigned u; } v; v.f = f;
  unsigned r = v.u + 0x7fffu + ((v.u >> 16) & 1u);   // RNE
  return (unsigned short)(r >> 16);
}
__device__ __forceinline__ float bf2f(unsigned short b) {
  union { unsigned u; float f; } v; v.u = ((unsigned)b) << 16;
  return v.f;
}
__device__ __forceinline__ float sigm(float x)  { return 1.f / (1.f + __expf(-x)); }
__device__ __forceinline__ float tanhx(float x) { return 2.f / (1.f + __expf(-2.f * x)) - 1.f; }

// ---------------- Phase A: x fp32 -> bf16 ----------------
__global__ __launch_bounds__(256) void k_cvt(const float* __restrict__ x,
                                             unsigned short* __restrict__ xb, int n4) {
  int stride = gridDim.x * blockDim.x;
  for (int i = blockIdx.x * blockDim.x + threadIdx.x; i < n4; i += stride) {
    float4 v = ((const float4*)x)[i];
    ushort4 o;
    o.x = f2bf(v.x); o.y = f2bf(v.y); o.z = f2bf(v.z); o.w = f2bf(v.w);
    ((ushort4*)xb)[i] = o;
  }
}

// ---------------- Phase A: W_i -> Wt[p][k] bf16 (p = j*64 + g*16 + hl), bias ----------------
__global__ __launch_bounds__(128) void k_prep_w(
    const float* __restrict__ wi, const float* __restrict__ wf,
    const float* __restrict__ wg, const float* __restrict__ wo,
    const float* __restrict__ bii, const float* __restrict__ bif,
    const float* __restrict__ big, const float* __restrict__ bio,
    const float* __restrict__ bhi, const float* __restrict__ bhf,
    const float* __restrict__ bhg, const float* __restrict__ bho,
    unsigned short* __restrict__ Wt, float* __restrict__ biasp) {
  int p = blockIdx.x;
  int g = (p >> 4) & 3, jj = p >> 6, hl = p & 15;
  int hcol = jj * 16 + hl;
  const float* w = (g == 0) ? wi : (g == 1) ? wf : (g == 2) ? wg : wo;
  for (int k = threadIdx.x; k < 512; k += 128)
    Wt[(long)p * 512 + k] = f2bf(w[(long)k * 512 + hcol]);
  if (threadIdx.x == 0) {
    const float* bi = (g == 0) ? bii : (g == 1) ? bif : (g == 2) ? big : bio;
    const float* bh = (g == 0) ? bhi : (g == 1) ? bhf : (g == 2) ? bhg : bho;
    biasp[p] = bi[hcol] + bh[hcol];
  }
}

// ---------------- Phase B: Gx = x @ Wt^T + bias (bf16 MFMA, 128x128 tile, BK=64) ----------------
__global__ __launch_bounds__(256) void k_gemm_x(
    const unsigned short* __restrict__ A,   // [131072][512] bf16
    const unsigned short* __restrict__ Bt,  // [2048][512] bf16
    const float* __restrict__ biasp,        // [2048]
    unsigned short* __restrict__ Gx) {      // [T][32][4][16][64] bf16
  __shared__ unsigned short lds[16384];     // 32 KB: lA[128][64] | lB[128][64], reused for epilogue
  unsigned short* lA = lds;
  unsigned short* lB = lds + 8192;
  const int tid  = threadIdx.x;
  const int lane = tid & 63;
  const int wave = tid >> 6;
  const long m0  = (long)blockIdx.x * 128;
  const int p0   = blockIdx.y * 128;
  const int wm   = (wave >> 1) * 64;
  const int wn   = (wave & 1) * 64;
  const int lrow = lane & 15;
  const int quad = lane >> 4;

  f32x4 acc[4][4] = {};

  for (int kb = 0; kb < 512; kb += 64) {
    __syncthreads();
#pragma unroll
    for (int it = 0; it < 4; ++it) {          // stage 128 rows x 64 k, XOR-swizzled (16B units)
      int ci = it * 256 + tid;
      int row = ci >> 3, c8 = ci & 7;
      int c8p = c8 ^ (row & 7);
      *(int4*)&lA[row * 64 + c8p * 8] = *(const int4*)(A + (m0 + row) * 512 + kb + c8 * 8);
      *(int4*)&lB[row * 64 + c8p * 8] = *(const int4*)(Bt + (long)(p0 + row) * 512 + kb + c8 * 8);
    }
    __syncthreads();
#pragma unroll
    for (int kk = 0; kk < 2; ++kk) {
      int c8 = kk * 4 + quad;
      bf16x8 af[4], bfr[4];
#pragma unroll
      for (int i = 0; i < 4; ++i) {
        int m = wm + i * 16 + lrow;
        af[i]  = *(const bf16x8*)&lA[m * 64 + ((c8 ^ (m & 7)) * 8)];
        int p = wn + i * 16 + lrow;
        bfr[i] = *(const bf16x8*)&lB[p * 64 + ((c8 ^ (p & 7)) * 8)];
      }
#pragma unroll
      for (int i = 0; i < 4; ++i)
#pragma unroll
        for (int n = 0; n < 4; ++n)
          acc[i][n] = __builtin_amdgcn_mfma_f32_16x16x32_bf16(af[i], bfr[n], acc[i][n], 0, 0, 0);
    }
  }

  float bl[4];
#pragma unroll
  for (int n = 0; n < 4; ++n) bl[n] = biasp[p0 + wn + n * 16 + lrow];

  __syncthreads();
#pragma unroll
  for (int i = 0; i < 4; ++i)
#pragma unroll
    for (int n = 0; n < 4; ++n) {
      int col = wn + n * 16 + lrow;
#pragma unroll
      for (int r4 = 0; r4 < 4; ++r4) {
        int row = wm + i * 16 + quad * 4 + r4;          // C/D: col=lane&15, row=quad*4+reg
        lds[row * 128 + col] = f2bf(acc[i][n][r4] + bl[n]);
      }
    }
  __syncthreads();
  {
    int row = tid >> 1, half = tid & 1;
    long m = m0 + row;
    int b = (int)(m >> 11), t = (int)(m & 2047);
    int bg = b >> 4, r = b & 15;
    int jj = (p0 >> 6) + half;
    unsigned short* dst = Gx + ((((long)t * 32 + jj) * 4 + bg) * 16 + r) * 64;
    const unsigned short* src = lds + row * 128 + half * 64;
#pragma unroll
    for (int c = 0; c < 8; ++c)
      *(int4*)(dst + c * 8) = *(const int4*)(src + c * 8);
  }
}

// ---------------- Phase C: persistent recurrence ----------------
// 128 wgs = 4 batch-groups (16 rows) x 32 col-wgs (16 hcols x 4 gates).
// wave w computes gate w; W_h fragment slice pinned in VGPRs for all 2048 steps.
// h exchange + flags use RELAXED agent-scope atomics (sc1, LLC-coherent, no
// buffer_inv/buffer_wbl2 cache maintenance).
__global__ __launch_bounds__(256, 1) void k_lstm(
    const float* __restrict__ Whi, const float* __restrict__ Whf,
    const float* __restrict__ Whg, const float* __restrict__ Who,
    const unsigned short* __restrict__ Gx,
    unsigned short* __restrict__ hbuf,   // [2][4][16][512] bf16, zeroed
    unsigned int* __restrict__ flags,    // [4][32], zeroed
    float* __restrict__ out) {
  const int wg   = blockIdx.x;
  const int bg   = wg >> 5;
  const int j    = wg & 31;
  const int tid  = threadIdx.x;
  const int lane = tid & 63;
  const int wave = tid >> 6;          // gate id
  const int hl   = lane & 15;
  const int quad = lane >> 4;

  __shared__ float gl[4][16][16];     // [gate][r][hl] raw h-part

  const float* Wh = (wave == 0) ? Whi : (wave == 1) ? Whf : (wave == 2) ? Whg : Who;
  const int hcol = j * 16 + hl;
  union WFrag { bf16x8 v; unsigned u[4]; };
  WFrag wfrag[16];                    // B-operand: B[k][n=lane&15], k = kk*32 + quad*8 + i
#pragma unroll
  for (int kk = 0; kk < 16; ++kk) {
    int kbase = kk * 32 + quad * 8;
    bf16x8 t;
#pragma unroll
    for (int i = 0; i < 8; ++i)
      t[i] = (short)f2bf(Wh[(long)(kbase + i) * 512 + hcol]);
    wfrag[kk].v = t;
  }
  // Pin the weight fragments in VGPRs: opaque to rematerialization/sinking.
#pragma unroll
  for (int kk = 0; kk < 16; ++kk) {
#pragma unroll
    for (int r = 0; r < 4; ++r)
      asm volatile("" : "+v"(wfrag[kk].u[r]));
  }

  unsigned short* hb0 = hbuf;
  unsigned short* hb1 = hbuf + 4 * 16 * 512;
  unsigned int* myflags = flags + bg * 32;
  const int fl  = lane & 31;
  const int er  = tid >> 4;           // epilogue row (batch row within group)
  const int ehl = tid & 15;           // epilogue hcol low
  const int r_a = lane & 15;          // MFMA A row

  float c_val = 0.f;
  float h_val = 0.f;

  for (int s = 0; s < T_STEPS; ++s) {
    // x-gate contributions: independent of h, issue before the poll.
    const unsigned short* gxp = Gx + ((((long)s * 32 + j) * 4 + bg) * 16 + er) * 64 + ehl;
    unsigned short gxi = gxp[0], gxf = gxp[16], gxg = gxp[32], gxo = gxp[48];

    if (s > 0) {
      // one flag per lane (lanes 32..63 duplicate), one wave-load per poll
      for (;;) {
        unsigned v = __hip_atomic_load(&myflags[fl], __ATOMIC_RELAXED,
                                       __HIP_MEMORY_SCOPE_AGENT);
        if (__all((int)(v >= (unsigned)s))) break;
        __builtin_amdgcn_s_sleep(1);
      }
    }
    const unsigned short* hcur = (s & 1) ? hb1 : hb0;
    unsigned short* hnxt       = (s & 1) ? hb0 : hb1;

    // A fragments: h[r = lane&15][k], via LLC-coherent 8B atomic loads
    const unsigned long long* hq =
        (const unsigned long long*)(hcur + (bg * 16 + r_a) * 512 + quad * 8);
    bf16x8 af[16];
#pragma unroll
    for (int kk = 0; kk < 16; ++kk) {
      union { unsigned long long q[2]; bf16x8 v; } u;
      u.q[0] = __hip_atomic_load(hq + kk * 8,     __ATOMIC_RELAXED, __HIP_MEMORY_SCOPE_AGENT);
      u.q[1] = __hip_atomic_load(hq + kk * 8 + 1, __ATOMIC_RELAXED, __HIP_MEMORY_SCOPE_AGENT);
      af[kk] = u.v;
    }

    f32x4 acc = {0.f, 0.f, 0.f, 0.f};
#pragma unroll
    for (int kk = 0; kk < 16; ++kk)
      acc = __builtin_amdgcn_mfma_f32_16x16x32_bf16(af[kk], wfrag[kk].v, acc, 0, 0, 0);

#pragma unroll
    for (int i = 0; i < 4; ++i)
      gl[wave][quad * 4 + i][hl] = acc[i];
    __syncthreads();

    float ui = gl[0][er][ehl] + bf2f(gxi);
    float uf = gl[1][er][ehl] + bf2f(gxf);
    float ug = gl[2][er][ehl] + bf2f(gxg);
    float uo = gl[3][er][ehl] + bf2f(gxo);
    float ig = sigm(ui), fg = sigm(uf), gg = tanhx(ug), og = sigm(uo);
    c_val = fg * c_val + ig * gg;
    h_val = og * tanhx(c_val);

    // pack 2 bf16 per lane-pair, store via LLC-coherent relaxed atomic
    unsigned hv = (unsigned)f2bf(h_val);
    unsigned other = (unsigned)__shfl_xor((int)hv, 1, 64);
    if ((tid & 1) == 0) {
      unsigned pack = (hv & 0xffffu) | (other << 16);   // low short = ehl, high = ehl+1
      unsigned* hn32 = (unsigned*)hnxt;
      int idx = ((bg * 16 + er) * 512 + j * 16 + ehl) >> 1;
      __hip_atomic_store(&hn32[idx], pack, __ATOMIC_RELAXED, __HIP_MEMORY_SCOPE_AGENT);
    }
    asm volatile("s_waitcnt vmcnt(0)" ::: "memory");   // own h stores acked at LLC
    __syncthreads();                                   // all threads' stores acked; guards gl reuse
    if (tid == 0)
      __hip_atomic_store(&myflags[j], (unsigned)(s + 1), __ATOMIC_RELAXED,
                         __HIP_MEMORY_SCOPE_AGENT);
  }

  int b = bg * 16 + er;
  out[(long)b * 512 + j * 16 + ehl]         = h_val;   // h_T
  out[32768 + (long)b * 512 + j * 16 + ehl] = c_val;   // c_T
}

// ---------------- launcher ----------------
extern "C" void kernel_launch(void* const* d_in, const int* in_sizes, int n_in,
                              void* d_out, int out_size, void* d_ws, size_t ws_size,
                              hipStream_t stream) {
  const float* x    = (const float*)d_in[0];
  const float* w_ii = (const float*)d_in[1];
  const float* w_hi = (const float*)d_in[2];
  const float* b_ii = (const float*)d_in[3];
  const float* b_hi = (const float*)d_in[4];
  const float* w_if = (const float*)d_in[5];
  const float* w_hf = (const float*)d_in[6];
  const float* b_if_= (const float*)d_in[7];
  const float* b_hf = (const float*)d_in[8];
  const float* w_ig = (const float*)d_in[9];
  const float* w_hg = (const float*)d_in[10];
  const float* b_ig = (const float*)d_in[11];
  const float* b_hg = (const float*)d_in[12];
  const float* w_io = (const float*)d_in[13];
  const float* w_ho = (const float*)d_in[14];
  const float* b_io = (const float*)d_in[15];
  const float* b_ho = (const float*)d_in[16];

  char* ws = (char*)d_ws;
  // layout: Gx 512MB | xb 128MB | Wt 2MB | biasp 8KB | hbuf 128KB | flags 512B
  unsigned short* Gx   = (unsigned short*)(ws);
  unsigned short* xb   = (unsigned short*)(ws + 536870912L);
  unsigned short* Wt   = (unsigned short*)(ws + 671088640L);
  float* biasp         = (float*)(ws + 673185792L);
  unsigned short* hbuf = (unsigned short*)(ws + 673193984L);
  // flags directly after hbuf (contiguous for one memset)

  hipMemsetAsync(hbuf, 0, 131072 + 512, stream);
  unsigned int* flags = (unsigned int*)(ws + 673193984L + 131072L);

  k_cvt<<<8192, 256, 0, stream>>>(x, xb, (64 * 2048 * 512) / 4);
  k_prep_w<<<2048, 128, 0, stream>>>(w_ii, w_if, w_ig, w_io,
                                     b_ii, b_if_, b_ig, b_io,
                                     b_hi, b_hf, b_hg, b_ho,
                                     Wt, biasp);
  k_gemm_x<<<dim3(1024, 16), 256, 0, stream>>>(xb, Wt, biasp, Gx);
  k_lstm<<<128, 256, 0, stream>>>(w_hi, w_hf, w_hg, w_ho, Gx, hbuf, flags, (float*)d_out);
}